// Round 3
// baseline (904.013 us; speedup 1.0000x reference)
//
#include <hip/hip_runtime.h>

// ---------------------------------------------------------------------------
// DrugCell-style VNN. R7: gemm_bt 256x256 8-phase pipeline, waves re-tiled
// 4Mx2N (wave tile 64Mx128N) so A-frags (av[4][2], 32 VGPR) persist across
// the whole K-step: LDS reads drop 32 -> 24 b128/wave/step (the floor for
// 8 waves), phases balanced 8/8/4/4. Staging: each wave stages its own A
// slices + its B-half-group slice (4+4 gl2lds at p2/p3); per-wave vmcnt(0)
// at p4 drains loads issued >=2 phases earlier (latency fully covered).
// ---------------------------------------------------------------------------

typedef float f32x4 __attribute__((ext_vector_type(4)));
typedef __bf16 bf16x8 __attribute__((ext_vector_type(8)));

#define GL2LDS(g, l)                                                          \
  __builtin_amdgcn_global_load_lds(                                           \
      (__attribute__((address_space(1))) void*)(g),                           \
      (__attribute__((address_space(3))) void*)(l), 16, 0, 0)

__device__ __forceinline__ unsigned short f2bf(float f) {
  unsigned int u = __float_as_uint(f);
  u = u + 0x7fffu + ((u >> 16) & 1u);   // round-to-nearest-even
  return (unsigned short)(u >> 16);
}

__device__ __forceinline__ float bf2f(unsigned int lo16) {
  return __uint_as_float(lo16 << 16);
}

__device__ __forceinline__ float tanh_fast(float x) {
  float e = __expf(2.0f * x);
  return 1.0f - __fdividef(2.0f, e + 1.0f);
}

// ---------------------------------------------------------------------------
// fp32 -> bf16 conversion of x and Wg in one launch
// ---------------------------------------------------------------------------
__global__ __launch_bounds__(256) void cvt_all(
    const float* __restrict__ x, const float* __restrict__ wg,
    unsigned short* __restrict__ xb, unsigned short* __restrict__ wgb) {
  constexpr int NX = 12320768 / 4;
  constexpr int NW = 49283072 / 4;
  int i = blockIdx.x * 256 + threadIdx.x;
  const float* src;
  unsigned short* dst;
  int j;
  if (i < NX) {
    src = x; dst = xb; j = i;
  } else {
    j = i - NX;
    if (j >= NW) return;
    src = wg; dst = wgb;
  }
  float4 v = ((const float4*)src)[j];
  ushort4 o;
  o.x = f2bf(v.x); o.y = f2bf(v.y); o.z = f2bf(v.z); o.w = f2bf(v.w);
  ((ushort4*)dst)[j] = o;
}

// ---------------------------------------------------------------------------
// bf16 GEMM: C(4096x16384) = A(MxK)*B(NxK)^T + bias[n], K=3008.
// LDS half-tile slot = 128 rows x 64 cols bf16 (16 KB). Row r, k-chunk c
// (8 elems) stored at chunk (c ^ (r&7)) -> conflict-free ds_read_b128 and
// linear gl2lds dest (source pre-swizzled per lane).
// A slots [par][half] at (par*2+h)*8192 elems; B same at +32768.
// Waves: wm=(w>>1)*64 (A-half ah=w>>2), wn=(w&1)*128 (B-half bg=w&1).
// Phases per K-step: (q,kk) = (0,0),(0,1),(1,0),(1,1); q = wave-local
// N-quarter. av[m][kk] live whole step; bv[4] reloaded per phase.
// ---------------------------------------------------------------------------
__global__ __launch_bounds__(512, 2) void gemm_bt(
    const unsigned short* __restrict__ A, const unsigned short* __restrict__ Bm,
    const float* __restrict__ bias, unsigned short* __restrict__ C) {
  constexpr int N = 16384, K = 3008;
  __shared__ unsigned short lds[65536];  // 128 KiB
  const int tid = threadIdx.x;
  const int w = tid >> 6, l = tid & 63;
  const int m0 = blockIdx.y * 256, n0 = blockIdx.x * 256;

  const int quad = l >> 4, lrow = l & 15;
  const int wm = (w >> 1) * 64;   // block-local M base of wave
  const int ah = w >> 2;          // A half this wave reads
  const int bg = w & 1;           // B half this wave reads/stages
  const int wn = bg * 128;        // block-local N base of wave

#define ASLOT(par, h) (lds + (((par) * 2 + (h)) * 8192))
#define BSLOT(par, h) (lds + 32768 + (((par) * 2 + (h)) * 8192))

  // ---- staging addressing (per-lane pre-swizzled source, linear LDS dest)
  // A: wave w stages rows [w*8, w*8+8) of each 64-row stripe (2 instr/half).
  const int r0 = tid >> 3;                  // 0..63
  const int c0 = (tid & 7) ^ (r0 & 7);
  const unsigned short* gA = A + (size_t)(m0 + r0) * K + c0 * 8;
  // B: group bg (4 waves) stages half bg; wave covers 32 rows (4 instr).
  const int wg = w >> 1;                    // 0..3 index within group
  const int brl = l >> 3;                   // 0..7
  const int bcl = (l & 7) ^ brl;
  const unsigned short* gBs =
      Bm + (size_t)(n0 + bg * 128 + wg * 32 + brl) * K + bcl * 8;
  const int bDst = wg * 2048;               // elem offset in B half slot

#define STAGEA(par, h, kofE)                                                  \
  do {                                                                        \
    unsigned short* d_ = ASLOT(par, h) + w * 512;                             \
    GL2LDS(gA + (size_t)((h) * 128) * K + (kofE), d_);                        \
    GL2LDS(gA + (size_t)((h) * 128 + 64) * K + (kofE), d_ + 4096);            \
  } while (0)
#define STAGEB2(par, j0, kofE)                                                \
  do {                                                                        \
    unsigned short* d_ = BSLOT(par, bg) + bDst + (j0) * 512;                  \
    GL2LDS(gBs + (size_t)((j0) * 8) * K + (kofE), d_);                        \
    GL2LDS(gBs + (size_t)((j0) * 8 + 8) * K + (kofE), d_ + 512);              \
  } while (0)

  // ---- fragment read offsets (elems within a half-tile slot)
  int aOff[2][4], bOff[2][4];
#pragma unroll
  for (int m = 0; m < 4; ++m) {
    int rh = (wm & 127) + m * 16 + lrow;    // row within A half
#pragma unroll
    for (int kk = 0; kk < 2; ++kk)
      aOff[kk][m] = rh * 64 + (((kk * 4 + quad) ^ (lrow & 7)) * 8);
  }
#pragma unroll
  for (int n = 0; n < 4; ++n) {
    int rh = n * 16 + lrow;                 // q adds 64 rows = 4096 elems
#pragma unroll
    for (int kk = 0; kk < 2; ++kk)
      bOff[kk][n] = rh * 64 + (((kk * 4 + quad) ^ (lrow & 7)) * 8);
  }

  f32x4 acc[4][8];
#pragma unroll
  for (int i = 0; i < 4; ++i)
#pragma unroll
    for (int j = 0; j < 8; ++j) acc[i][j] = (f32x4)0.0f;
  bf16x8 av[4][2], bv[4];

#define VM0 asm volatile("s_waitcnt vmcnt(0)" ::: "memory")
#define NOVM ((void)0)
#define NOSTG ((void)0)

#define PHASE(par, q, kk, LA, STG, VMAFTER)                                   \
  {                                                                           \
    if (LA) {                                                                 \
      _Pragma("unroll") for (int m = 0; m < 4; ++m)                           \
          av[m][kk] = *(const bf16x8*)(ASLOT(par, ah) + aOff[kk][m]);         \
    }                                                                         \
    _Pragma("unroll") for (int n = 0; n < 4; ++n)                             \
        bv[n] = *(const bf16x8*)(BSLOT(par, bg) + bOff[kk][n] + (q) * 4096);  \
    STG;                                                                      \
    __builtin_amdgcn_s_barrier();                                             \
    asm volatile("s_waitcnt lgkmcnt(0)" ::: "memory");                        \
    __builtin_amdgcn_sched_barrier(0);                                        \
    __builtin_amdgcn_s_setprio(1);                                            \
    _Pragma("unroll") for (int m = 0; m < 4; ++m)                             \
      _Pragma("unroll") for (int n = 0; n < 4; ++n)                           \
          acc[m][(q) * 4 + n] = __builtin_amdgcn_mfma_f32_16x16x32_bf16(      \
              av[m][kk], bv[n], acc[m][(q) * 4 + n], 0, 0, 0);                \
    __builtin_amdgcn_s_setprio(0);                                            \
    VMAFTER;                                                                  \
    __builtin_amdgcn_sched_barrier(0);                                        \
    __builtin_amdgcn_s_barrier();                                             \
  }

  // staging lives at p2/p3 (light-read phases follow); vmcnt(0) at p4 drains
  // loads issued >=2 phases earlier (per-wave own loads; ~2300 cyc cover)
#define FULLSTEP(par)                                                         \
  PHASE(par, 0, 0, true, NOSTG, NOVM);                                        \
  PHASE(par, 0, 1, true,                                                      \
        STAGEA((par) ^ 1, 0, kof + 64); STAGEB2((par) ^ 1, 0, kof + 64),      \
        NOVM);                                                                \
  PHASE(par, 1, 0, false,                                                     \
        STAGEA((par) ^ 1, 1, kof + 64); STAGEB2((par) ^ 1, 2, kof + 64),      \
        NOVM);                                                                \
  PHASE(par, 1, 1, false, NOSTG, VM0);                                        \
  kof += 64;

#define LASTSTEP(par)                                                         \
  PHASE(par, 0, 0, true, NOSTG, NOVM);                                        \
  PHASE(par, 0, 1, true, NOSTG, NOVM);                                        \
  PHASE(par, 1, 0, false, NOSTG, NOVM);                                       \
  PHASE(par, 1, 1, false, NOSTG, NOVM);

  // prologue: stage step 0 into parity 0, drain, barrier
  STAGEA(0, 0, 0); STAGEA(0, 1, 0); STAGEB2(0, 0, 0); STAGEB2(0, 2, 0);
  VM0;
  __builtin_amdgcn_s_barrier();

  int kof = 0;
  for (int it = 0; it < 23; ++it) {  // steps 0..45
    FULLSTEP(0);
    FULLSTEP(1);
  }
  LASTSTEP(0);                       // step 46

#undef FULLSTEP
#undef LASTSTEP
#undef PHASE
#undef STAGEA
#undef STAGEB2
#undef ASLOT
#undef BSLOT

  // epilogue: C/D layout col=lane&15, row=quad*4+reg
#pragma unroll
  for (int nf = 0; nf < 8; ++nf) {
    int n = n0 + wn + nf * 16 + lrow;
    float bnv = bias[n];
#pragma unroll
    for (int m = 0; m < 4; ++m) {
      int mbase = m0 + wm + m * 16 + quad * 4;
#pragma unroll
      for (int r = 0; r < 4; ++r)
        C[(size_t)(mbase + r) * N + n] = f2bf(acc[m][nf][r] + bnv);
    }
  }
}

// ---------------------------------------------------------------------------
// row loaders (term-slice of IC elements)
// ---------------------------------------------------------------------------
template <int IC>
__device__ __forceinline__ void load_row(const unsigned short* p, float* d) {
  static_assert(IC % 8 == 0, "");
#pragma unroll
  for (int i = 0; i < IC / 8; ++i) {
    uint4 u = *(const uint4*)(p + i * 8);
    d[i * 8 + 0] = bf2f(u.x & 0xffffu); d[i * 8 + 1] = bf2f(u.x >> 16);
    d[i * 8 + 2] = bf2f(u.y & 0xffffu); d[i * 8 + 3] = bf2f(u.y >> 16);
    d[i * 8 + 4] = bf2f(u.z & 0xffffu); d[i * 8 + 5] = bf2f(u.z >> 16);
    d[i * 8 + 6] = bf2f(u.w & 0xffffu); d[i * 8 + 7] = bf2f(u.w >> 16);
  }
}
template <int IC>
__device__ __forceinline__ void load_row(const float* p, float* d) {
  static_assert(IC % 4 == 0, "");
#pragma unroll
  for (int i = 0; i < IC / 4; ++i) {
    float4 v = *(const float4*)(p + i * 4);
    d[i * 4 + 0] = v.x; d[i * 4 + 1] = v.y;
    d[i * 4 + 2] = v.z; d[i * 4 + 3] = v.w;
  }
}

// ---------------------------------------------------------------------------
// Term layer: block = TG terms x (4096/gridDim.y) b's; tid = bsub*TG + t.
// Wave lanes cover consecutive terms -> contiguous row-slice reads.
// ---------------------------------------------------------------------------
template <typename TIN, typename TOUT, int T, int IC, int TG, bool FIRST>
__global__ __launch_bounds__(256) void term_layer(
    const TIN* __restrict__ in, const float* __restrict__ prevStats,
    const float* __restrict__ prevGm, const float* __restrict__ prevBt,
    const float* __restrict__ W, const float* __restrict__ bvec,
    TOUT* __restrict__ out, float* __restrict__ curStats) {
  constexpr int WIN = T * IC;
  constexpr int WOUT = T * 6;
  constexpr int NB = 256 / TG;
  const int tb = blockIdx.x * TG;
  const int t = threadIdx.x & (TG - 1);
  const int bsub = threadIdx.x / TG;

  __shared__ float sW[TG * 6 * IC];
  __shared__ float sB[TG * 6];
  __shared__ float sScale[FIRST ? 1 : TG * IC];
  __shared__ float sShift[FIRST ? 1 : TG * IC];
  __shared__ float sRed[256][13];  // 13: odd stride, conflict-free

  for (int i = threadIdx.x; i < TG * 6 * IC; i += 256)
    sW[i] = W[(size_t)tb * 6 * IC + i];
  for (int i = threadIdx.x; i < TG * 6; i += 256) sB[i] = bvec[tb * 6 + i];
  if constexpr (!FIRST) {
    for (int i = threadIdx.x; i < TG * IC; i += 256) {
      int gc = tb * IC + i;
      float mu = prevStats[gc] * (1.0f / 4096.0f);
      float var = prevStats[WIN + gc] * (1.0f / 4096.0f) - mu * mu;
      float sc = rsqrtf(var + 1e-5f) * prevGm[gc];
      sScale[i] = sc;
      sShift[i] = prevBt[gc] - mu * sc;
    }
  }
  __syncthreads();

  float ls[6], lq[6];
#pragma unroll
  for (int i = 0; i < 6; ++i) { ls[i] = 0.0f; lq[i] = 0.0f; }

  const int bchunk = 4096 / gridDim.y;
  const int rows = bchunk / NB;
  const int b0 = blockIdx.y * bchunk + bsub * rows;
  for (int i = 0; i < rows; ++i) {
    int b = b0 + i;
    float child[IC];
    load_row<IC>(in + (size_t)b * WIN + (size_t)(tb + t) * IC, child);
    if constexpr (!FIRST) {
#pragma unroll
      for (int c = 0; c < IC; ++c)
        child[c] = child[c] * sScale[t * IC + c] + sShift[t * IC + c];
    }
    float hv[6];
#pragma unroll
    for (int o = 0; o < 6; ++o) {
      float a = sB[t * 6 + o];
      const float* wr = &sW[(t * 6 + o) * IC];
#pragma unroll
      for (int j = 0; j < IC; ++j) a += child[j] * wr[j];
      float h = tanh_fast(a);
      hv[o] = h;
      ls[o] += h;
      lq[o] += h * h;
    }
    TOUT* op = out + (size_t)b * WOUT + (size_t)(tb + t) * 6;
    if constexpr (sizeof(TOUT) == 2) {
      unsigned int* oi = (unsigned int*)op;
#pragma unroll
      for (int i2 = 0; i2 < 3; ++i2)
        oi[i2] = (unsigned int)f2bf(hv[2 * i2]) |
                 ((unsigned int)f2bf(hv[2 * i2 + 1]) << 16);
    } else {
#pragma unroll
      for (int i2 = 0; i2 < 6; ++i2) op[i2] = hv[i2];
    }
  }

  // stats: stage per-thread partials, reduce over NB bsubs, 1 atomic each
#pragma unroll
  for (int j = 0; j < 6; ++j) {
    sRed[threadIdx.x][j] = ls[j];
    sRed[threadIdx.x][6 + j] = lq[j];
  }
  __syncthreads();
  for (int i = threadIdx.x; i < TG * 6; i += 256) {
    int tt = i / 6, o = i % 6;
    float s = 0.0f, q = 0.0f;
    for (int nb = 0; nb < NB; ++nb) {
      s += sRed[nb * TG + tt][o];
      q += sRed[nb * TG + tt][6 + o];
    }
    atomicAdd(&curStats[(tb + tt) * 6 + o], s);
    atomicAdd(&curStats[WOUT + (tb + tt) * 6 + o], q);
  }
}

// ---------------------------------------------------------------------------
// Final: root = BN(h5) -> out(4096x768) = root @ Wf^T + bf
// ---------------------------------------------------------------------------
__global__ __launch_bounds__(256) void final_fc(
    const float* __restrict__ h5, const float* __restrict__ stats5,
    const float* __restrict__ gm5, const float* __restrict__ bt5,
    const float* __restrict__ Wf, const float* __restrict__ bfv,
    float* __restrict__ out) {
  __shared__ float sWf[768 * 6];
  __shared__ float sbf[768];
  __shared__ float sRoot[8][6];
  const int tid = threadIdx.x;
  for (int i = tid; i < 768 * 6; i += 256) sWf[i] = Wf[i];
  for (int i = tid; i < 768; i += 256) sbf[i] = bfv[i];
  const int b0 = blockIdx.x * 8;
  if (tid < 48) {
    int bb = tid / 6, o = tid % 6;
    float mu = stats5[o] * (1.0f / 4096.0f);
    float var = stats5[6 + o] * (1.0f / 4096.0f) - mu * mu;
    float sc = rsqrtf(var + 1e-5f) * gm5[o];
    sRoot[bb][o] = (h5[(size_t)(b0 + bb) * 6 + o] - mu) * sc + bt5[o];
  }
  __syncthreads();
#pragma unroll
  for (int bb = 0; bb < 8; ++bb) {
    float r0 = sRoot[bb][0], r1 = sRoot[bb][1], r2 = sRoot[bb][2];
    float r3 = sRoot[bb][3], r4 = sRoot[bb][4], r5 = sRoot[bb][5];
    for (int d = tid; d < 768; d += 256) {
      const float* wr = &sWf[d * 6];
      float a = sbf[d] + r0 * wr[0] + r1 * wr[1] + r2 * wr[2] +
                r3 * wr[3] + r4 * wr[4] + r5 * wr[5];
      out[(size_t)(b0 + bb) * 768 + d] = a;
    }
  }
}

// ---------------------------------------------------------------------------
// launch
// ---------------------------------------------------------------------------
extern "C" void kernel_launch(void* const* d_in, const int* in_sizes, int n_in,
                              void* d_out, int out_size, void* d_ws,
                              size_t ws_size, hipStream_t stream) {
  const float* x   = (const float*)d_in[0];
  const float* Wg  = (const float*)d_in[1];
  const float* bg  = (const float*)d_in[2];
  const float* W0  = (const float*)d_in[3];
  const float* b0v = (const float*)d_in[4];
  const float* gm0 = (const float*)d_in[5];
  const float* bt0 = (const float*)d_in[6];
  const float* W1  = (const float*)d_in[7];
  const float* b1v = (const float*)d_in[8];
  const float* gm1 = (const float*)d_in[9];
  const float* bt1 = (const float*)d_in[10];
  const float* W2  = (const float*)d_in[11];
  const float* b2v = (const float*)d_in[12];
  const float* gm2 = (const float*)d_in[13];
  const float* bt2 = (const float*)d_in[14];
  const float* W3  = (const float*)d_in[15];
  const float* b3v = (const float*)d_in[16];
  const float* gm3 = (const float*)d_in[17];
  const float* bt3 = (const float*)d_in[18];
  const float* W4  = (const float*)d_in[19];
  const float* b4v = (const float*)d_in[20];
  const float* gm4 = (const float*)d_in[21];
  const float* bt4 = (const float*)d_in[22];
  const float* W5  = (const float*)d_in[23];
  const float* b5v = (const float*)d_in[24];
  const float* gm5 = (const float*)d_in[25];
  const float* bt5 = (const float*)d_in[26];
  const float* Wf  = (const float*)d_in[27];
  const float* bfv = (const float*)d_in[28];

  char* ws = (char*)d_ws;
  unsigned short* Xb  = (unsigned short*)(ws + 0);            // 24,641,536
  unsigned short* Wgb = (unsigned short*)(ws + 24641536ULL);  // 98,566,144
  unsigned short* G   = (unsigned short*)(ws + 123207680ULL); // 134,217,728
  unsigned short* h0  = (unsigned short*)(ws + 257425408ULL); // 100,663,296
  unsigned short* h1  = (unsigned short*)(ws + 358088704ULL); // 25,165,824
  unsigned short* h2  = (unsigned short*)(ws + 383254528ULL); //  6,291,456
  float* h3 = (float*)(ws + 389545984ULL);                    //  3,145,728
  float* h4 = (float*)(ws + 392691712ULL);                    //    786,432
  float* h5 = (float*)(ws + 393478144ULL);                    //     98,304
  float* stats = (float*)(ws + 393576448ULL);                 //    131,072

  hipMemsetAsync(stats, 0, 131072, stream);

  cvt_all<<<dim3(60160), 256, 0, stream>>>(x, Wg, Xb, Wgb);

  gemm_bt<<<dim3(64, 16), 512, 0, stream>>>(Xb, Wgb, bg, G);

  term_layer<unsigned short, unsigned short, 2048, 8, 64, true>
      <<<dim3(32, 64), 256, 0, stream>>>(G, nullptr, nullptr, nullptr, W0, b0v,
                                         h0, stats + 0);
  term_layer<unsigned short, unsigned short, 512, 24, 32, false>
      <<<dim3(16, 64), 256, 0, stream>>>(h0, stats + 0, gm0, bt0, W1, b1v, h1,
                                         stats + 24576);
  term_layer<unsigned short, unsigned short, 128, 24, 32, false>
      <<<dim3(4, 128), 256, 0, stream>>>(h1, stats + 24576, gm1, bt1, W2, b2v,
                                         h2, stats + 30720);
  term_layer<unsigned short, float, 32, 24, 32, false>
      <<<dim3(1, 128), 256, 0, stream>>>(h2, stats + 30720, gm2, bt2, W3, b3v,
                                         h3, stats + 32256);
  term_layer<float, float, 8, 24, 8, false>
      <<<dim3(1, 64), 256, 0, stream>>>(h3, stats + 32256, gm3, bt3, W4, b4v,
                                        h4, stats + 32640);
  term_layer<float, float, 1, 48, 1, false>
      <<<dim3(1, 16), 256, 0, stream>>>(h4, stats + 32640, gm4, bt4, W5, b5v,
                                        h5, stats + 32736);

  final_fc<<<dim3(512), 256, 0, stream>>>(h5, stats + 32736, gm5, bt5, Wf, bfv,
                                          (float*)d_out);
}

// Round 4
// 845.775 us; speedup vs baseline: 1.0689x; 1.0689x over previous
//
#include <hip/hip_runtime.h>

// ---------------------------------------------------------------------------
// DrugCell-style VNN. R8: gemm_bt 256x256, 8 waves 4Mx2N (24 ds_read/wave/
// step = floor), phase order (q0k0,q1k0,q0k1,q1k1) -> reads 8/4/8/4.
// Counted waits (T4): stage B(s+1)@p1/p2 into par^1, A(s+2)@p4 into par
// (A reads end at p3+barrier). End-of-step vmcnt(4) retires A(s+1) (age
// ~4 phases) + B(s+1) (2.5-3.5 ph), leaves A(s+2) in flight across the
// barrier -- retired by next step's wait before its read. No drain-to-0
// in main loop (R7's regression was a 1.2-phase-aged vmcnt(0) per step).
// ---------------------------------------------------------------------------

typedef float f32x4 __attribute__((ext_vector_type(4)));
typedef __bf16 bf16x8 __attribute__((ext_vector_type(8)));

#define GL2LDS(g, l)                                                          \
  __builtin_amdgcn_global_load_lds(                                           \
      (__attribute__((address_space(1))) void*)(g),                           \
      (__attribute__((address_space(3))) void*)(l), 16, 0, 0)

__device__ __forceinline__ unsigned short f2bf(float f) {
  unsigned int u = __float_as_uint(f);
  u = u + 0x7fffu + ((u >> 16) & 1u);   // round-to-nearest-even
  return (unsigned short)(u >> 16);
}

__device__ __forceinline__ float bf2f(unsigned int lo16) {
  return __uint_as_float(lo16 << 16);
}

__device__ __forceinline__ float tanh_fast(float x) {
  float e = __expf(2.0f * x);
  return 1.0f - __fdividef(2.0f, e + 1.0f);
}

// ---------------------------------------------------------------------------
// fp32 -> bf16 conversion of x and Wg in one launch
// ---------------------------------------------------------------------------
__global__ __launch_bounds__(256) void cvt_all(
    const float* __restrict__ x, const float* __restrict__ wg,
    unsigned short* __restrict__ xb, unsigned short* __restrict__ wgb) {
  constexpr int NX = 12320768 / 4;
  constexpr int NW = 49283072 / 4;
  int i = blockIdx.x * 256 + threadIdx.x;
  const float* src;
  unsigned short* dst;
  int j;
  if (i < NX) {
    src = x; dst = xb; j = i;
  } else {
    j = i - NX;
    if (j >= NW) return;
    src = wg; dst = wgb;
  }
  float4 v = ((const float4*)src)[j];
  ushort4 o;
  o.x = f2bf(v.x); o.y = f2bf(v.y); o.z = f2bf(v.z); o.w = f2bf(v.w);
  ((ushort4*)dst)[j] = o;
}

// ---------------------------------------------------------------------------
// bf16 GEMM: C(4096x16384) = A(MxK)*B(NxK)^T + bias[n], K=3008.
// LDS half-tile slot = 128 rows x 64 cols bf16 (16 KB). Row r, k-chunk c
// (8 elems) stored at chunk (c ^ (r&7)) -> conflict-free ds_read_b128 and
// linear gl2lds dest (source pre-swizzled per lane).
// A slots [par][half] at (par*2+h)*8192 elems; B same at +32768.
// Waves: wm=(w>>1)*64 (A-half ah=w>>2), wn=(w&1)*128 (B-half bg=w&1).
// Phases per K-step: (q,kk) = (0,0),(1,0),(0,1),(1,1); q = wave-local
// N-quarter. av[m][kk] live whole step; bv[4] reloaded per phase.
// ---------------------------------------------------------------------------
__global__ __launch_bounds__(512, 2) void gemm_bt(
    const unsigned short* __restrict__ A, const unsigned short* __restrict__ Bm,
    const float* __restrict__ bias, unsigned short* __restrict__ C) {
  constexpr int N = 16384, K = 3008;
  __shared__ unsigned short lds[65536];  // 128 KiB
  const int tid = threadIdx.x;
  const int w = tid >> 6, l = tid & 63;
  const int m0 = blockIdx.y * 256, n0 = blockIdx.x * 256;

  const int quad = l >> 4, lrow = l & 15;
  const int wm = (w >> 1) * 64;   // block-local M base of wave
  const int ah = w >> 2;          // A half this wave reads
  const int bg = w & 1;           // B half this wave reads/stages
  const int wn = bg * 128;        // block-local N base of wave

#define ASLOT(par, h) (lds + (((par) * 2 + (h)) * 8192))
#define BSLOT(par, h) (lds + 32768 + (((par) * 2 + (h)) * 8192))

  // ---- staging addressing (per-lane pre-swizzled source, linear LDS dest)
  // A: wave w stages rows [w*8, w*8+8) of each 64-row stripe (2 instr/half).
  const int r0 = tid >> 3;                  // 0..63
  const int c0 = (tid & 7) ^ (r0 & 7);
  const unsigned short* gA = A + (size_t)(m0 + r0) * K + c0 * 8;
  // B: group bg (4 waves) stages half bg; wave covers 32 rows (4 instr).
  const int wg = w >> 1;                    // 0..3 index within group
  const int brl = l >> 3;                   // 0..7
  const int bcl = (l & 7) ^ brl;
  const unsigned short* gBs =
      Bm + (size_t)(n0 + bg * 128 + wg * 32 + brl) * K + bcl * 8;
  const int bDst = wg * 2048;               // elem offset in B half slot

#define STAGEA(par, h, kofE)                                                  \
  do {                                                                        \
    unsigned short* d_ = ASLOT(par, h) + w * 512;                             \
    GL2LDS(gA + (size_t)((h) * 128) * K + (kofE), d_);                        \
    GL2LDS(gA + (size_t)((h) * 128 + 64) * K + (kofE), d_ + 4096);            \
  } while (0)
#define STAGEB2(par, j0, kofE)                                                \
  do {                                                                        \
    unsigned short* d_ = BSLOT(par, bg) + bDst + (j0) * 512;                  \
    GL2LDS(gBs + (size_t)((j0) * 8) * K + (kofE), d_);                        \
    GL2LDS(gBs + (size_t)((j0) * 8 + 8) * K + (kofE), d_ + 512);              \
  } while (0)

  // ---- fragment read offsets (elems within a half-tile slot)
  int aOff[2][4], bOff[2][4];
#pragma unroll
  for (int m = 0; m < 4; ++m) {
    int rh = (wm & 127) + m * 16 + lrow;    // row within A half
#pragma unroll
    for (int kk = 0; kk < 2; ++kk)
      aOff[kk][m] = rh * 64 + (((kk * 4 + quad) ^ (lrow & 7)) * 8);
  }
#pragma unroll
  for (int n = 0; n < 4; ++n) {
    int rh = n * 16 + lrow;                 // q adds 64 rows = 4096 elems
#pragma unroll
    for (int kk = 0; kk < 2; ++kk)
      bOff[kk][n] = rh * 64 + (((kk * 4 + quad) ^ (lrow & 7)) * 8);
  }

  f32x4 acc[4][8];
#pragma unroll
  for (int i = 0; i < 4; ++i)
#pragma unroll
    for (int j = 0; j < 8; ++j) acc[i][j] = (f32x4)0.0f;
  bf16x8 av[4][2], bv[4];

#define VM4 asm volatile("s_waitcnt vmcnt(4)" ::: "memory")
#define VM0 asm volatile("s_waitcnt vmcnt(0)" ::: "memory")
#define NOVM ((void)0)
#define NOSTG ((void)0)

#define PHASE(par, q, kk, LA, STG, VMAFTER)                                   \
  {                                                                           \
    if (LA) {                                                                 \
      _Pragma("unroll") for (int m = 0; m < 4; ++m)                           \
          av[m][kk] = *(const bf16x8*)(ASLOT(par, ah) + aOff[kk][m]);         \
    }                                                                         \
    _Pragma("unroll") for (int n = 0; n < 4; ++n)                             \
        bv[n] = *(const bf16x8*)(BSLOT(par, bg) + bOff[kk][n] + (q) * 4096);  \
    STG;                                                                      \
    __builtin_amdgcn_s_barrier();                                             \
    asm volatile("s_waitcnt lgkmcnt(0)" ::: "memory");                        \
    __builtin_amdgcn_sched_barrier(0);                                        \
    __builtin_amdgcn_s_setprio(1);                                            \
    _Pragma("unroll") for (int m = 0; m < 4; ++m)                             \
      _Pragma("unroll") for (int n = 0; n < 4; ++n)                           \
          acc[m][(q) * 4 + n] = __builtin_amdgcn_mfma_f32_16x16x32_bf16(      \
              av[m][kk], bv[n], acc[m][(q) * 4 + n], 0, 0, 0);                \
    __builtin_amdgcn_s_setprio(0);                                            \
    VMAFTER;                                                                  \
    __builtin_amdgcn_sched_barrier(0);                                        \
    __builtin_amdgcn_s_barrier();                                             \
  }

  // Full step s (par = s&1): B(s+1) staged p1/p2 into par^1 (retired end of
  // step, age 2.5-3.5 phases); A(s+2) staged p4 into par, after A's last
  // read at p3 (stays in flight across the end barrier; retired by the
  // NEXT step's vmcnt(4), age ~4 phases, before its read in step s+2).
#define FULLSTEP(par)                                                         \
  PHASE(par, 0, 0, true, STAGEB2((par) ^ 1, 0, kof + 64), NOVM);              \
  PHASE(par, 1, 0, false, STAGEB2((par) ^ 1, 2, kof + 64), NOVM);             \
  PHASE(par, 0, 1, true, NOSTG, NOVM);                                        \
  PHASE(par, 1, 1, false,                                                     \
        STAGEA(par, 0, kof + 128); STAGEA(par, 1, kof + 128), VM4);           \
  kof += 64;

#define STEP45(par)                                                           \
  PHASE(par, 0, 0, true, STAGEB2((par) ^ 1, 0, kof + 64), NOVM);              \
  PHASE(par, 1, 0, false, STAGEB2((par) ^ 1, 2, kof + 64), NOVM);             \
  PHASE(par, 0, 1, true, NOSTG, NOVM);                                        \
  PHASE(par, 1, 1, false, NOSTG, VM0);                                        \
  kof += 64;

#define STEP46(par)                                                           \
  PHASE(par, 0, 0, true, NOSTG, NOVM);                                        \
  PHASE(par, 1, 0, false, NOSTG, NOVM);                                       \
  PHASE(par, 0, 1, true, NOSTG, NOVM);                                        \
  PHASE(par, 1, 1, false, NOSTG, NOVM);

  // prologue: A(0),B(0) into par0 (8 loads), A(1) into par1 (4 loads);
  // vmcnt(4) retires step-0 data, leaves A(1) in flight (steady invariant:
  // at each step start, exactly A(s+1) is outstanding).
  STAGEA(0, 0, 0); STAGEA(0, 1, 0); STAGEB2(0, 0, 0); STAGEB2(0, 2, 0);
  STAGEA(1, 0, 64); STAGEA(1, 1, 64);
  VM4;
  __builtin_amdgcn_s_barrier();

  int kof = 0;
  for (int it = 0; it < 22; ++it) {  // steps 0..43
    FULLSTEP(0);
    FULLSTEP(1);
  }
  FULLSTEP(0);                       // step 44 (stages B(45), A(46))
  STEP45(1);                         // step 45 (stages B(46); drain all)
  STEP46(0);                         // step 46 (compute only)

#undef FULLSTEP
#undef STEP45
#undef STEP46
#undef PHASE
#undef STAGEA
#undef STAGEB2
#undef ASLOT
#undef BSLOT

  // epilogue: C/D layout col=lane&15, row=quad*4+reg
#pragma unroll
  for (int nf = 0; nf < 8; ++nf) {
    int n = n0 + wn + nf * 16 + lrow;
    float bnv = bias[n];
#pragma unroll
    for (int m = 0; m < 4; ++m) {
      int mbase = m0 + wm + m * 16 + quad * 4;
#pragma unroll
      for (int r = 0; r < 4; ++r)
        C[(size_t)(mbase + r) * N + n] = f2bf(acc[m][nf][r] + bnv);
    }
  }
}

// ---------------------------------------------------------------------------
// row loaders (term-slice of IC elements)
// ---------------------------------------------------------------------------
template <int IC>
__device__ __forceinline__ void load_row(const unsigned short* p, float* d) {
  static_assert(IC % 8 == 0, "");
#pragma unroll
  for (int i = 0; i < IC / 8; ++i) {
    uint4 u = *(const uint4*)(p + i * 8);
    d[i * 8 + 0] = bf2f(u.x & 0xffffu); d[i * 8 + 1] = bf2f(u.x >> 16);
    d[i * 8 + 2] = bf2f(u.y & 0xffffu); d[i * 8 + 3] = bf2f(u.y >> 16);
    d[i * 8 + 4] = bf2f(u.z & 0xffffu); d[i * 8 + 5] = bf2f(u.z >> 16);
    d[i * 8 + 6] = bf2f(u.w & 0xffffu); d[i * 8 + 7] = bf2f(u.w >> 16);
  }
}
template <int IC>
__device__ __forceinline__ void load_row(const float* p, float* d) {
  static_assert(IC % 4 == 0, "");
#pragma unroll
  for (int i = 0; i < IC / 4; ++i) {
    float4 v = *(const float4*)(p + i * 4);
    d[i * 4 + 0] = v.x; d[i * 4 + 1] = v.y;
    d[i * 4 + 2] = v.z; d[i * 4 + 3] = v.w;
  }
}

// ---------------------------------------------------------------------------
// Term layer: block = TG terms x (4096/gridDim.y) b's; tid = bsub*TG + t.
// Wave lanes cover consecutive terms -> contiguous row-slice reads.
// ---------------------------------------------------------------------------
template <typename TIN, typename TOUT, int T, int IC, int TG, bool FIRST>
__global__ __launch_bounds__(256) void term_layer(
    const TIN* __restrict__ in, const float* __restrict__ prevStats,
    const float* __restrict__ prevGm, const float* __restrict__ prevBt,
    const float* __restrict__ W, const float* __restrict__ bvec,
    TOUT* __restrict__ out, float* __restrict__ curStats) {
  constexpr int WIN = T * IC;
  constexpr int WOUT = T * 6;
  constexpr int NB = 256 / TG;
  const int tb = blockIdx.x * TG;
  const int t = threadIdx.x & (TG - 1);
  const int bsub = threadIdx.x / TG;

  __shared__ float sW[TG * 6 * IC];
  __shared__ float sB[TG * 6];
  __shared__ float sScale[FIRST ? 1 : TG * IC];
  __shared__ float sShift[FIRST ? 1 : TG * IC];
  __shared__ float sRed[256][13];  // 13: odd stride, conflict-free

  for (int i = threadIdx.x; i < TG * 6 * IC; i += 256)
    sW[i] = W[(size_t)tb * 6 * IC + i];
  for (int i = threadIdx.x; i < TG * 6; i += 256) sB[i] = bvec[tb * 6 + i];
  if constexpr (!FIRST) {
    for (int i = threadIdx.x; i < TG * IC; i += 256) {
      int gc = tb * IC + i;
      float mu = prevStats[gc] * (1.0f / 4096.0f);
      float var = prevStats[WIN + gc] * (1.0f / 4096.0f) - mu * mu;
      float sc = rsqrtf(var + 1e-5f) * prevGm[gc];
      sScale[i] = sc;
      sShift[i] = prevBt[gc] - mu * sc;
    }
  }
  __syncthreads();

  float ls[6], lq[6];
#pragma unroll
  for (int i = 0; i < 6; ++i) { ls[i] = 0.0f; lq[i] = 0.0f; }

  const int bchunk = 4096 / gridDim.y;
  const int rows = bchunk / NB;
  const int b0 = blockIdx.y * bchunk + bsub * rows;
  for (int i = 0; i < rows; ++i) {
    int b = b0 + i;
    float child[IC];
    load_row<IC>(in + (size_t)b * WIN + (size_t)(tb + t) * IC, child);
    if constexpr (!FIRST) {
#pragma unroll
      for (int c = 0; c < IC; ++c)
        child[c] = child[c] * sScale[t * IC + c] + sShift[t * IC + c];
    }
    float hv[6];
#pragma unroll
    for (int o = 0; o < 6; ++o) {
      float a = sB[t * 6 + o];
      const float* wr = &sW[(t * 6 + o) * IC];
#pragma unroll
      for (int j = 0; j < IC; ++j) a += child[j] * wr[j];
      float h = tanh_fast(a);
      hv[o] = h;
      ls[o] += h;
      lq[o] += h * h;
    }
    TOUT* op = out + (size_t)b * WOUT + (size_t)(tb + t) * 6;
    if constexpr (sizeof(TOUT) == 2) {
      unsigned int* oi = (unsigned int*)op;
#pragma unroll
      for (int i2 = 0; i2 < 3; ++i2)
        oi[i2] = (unsigned int)f2bf(hv[2 * i2]) |
                 ((unsigned int)f2bf(hv[2 * i2 + 1]) << 16);
    } else {
#pragma unroll
      for (int i2 = 0; i2 < 6; ++i2) op[i2] = hv[i2];
    }
  }

  // stats: stage per-thread partials, reduce over NB bsubs, 1 atomic each
#pragma unroll
  for (int j = 0; j < 6; ++j) {
    sRed[threadIdx.x][j] = ls[j];
    sRed[threadIdx.x][6 + j] = lq[j];
  }
  __syncthreads();
  for (int i = threadIdx.x; i < TG * 6; i += 256) {
    int tt = i / 6, o = i % 6;
    float s = 0.0f, q = 0.0f;
    for (int nb = 0; nb < NB; ++nb) {
      s += sRed[nb * TG + tt][o];
      q += sRed[nb * TG + tt][6 + o];
    }
    atomicAdd(&curStats[(tb + tt) * 6 + o], s);
    atomicAdd(&curStats[WOUT + (tb + tt) * 6 + o], q);
  }
}

// ---------------------------------------------------------------------------
// Final: root = BN(h5) -> out(4096x768) = root @ Wf^T + bf
// ---------------------------------------------------------------------------
__global__ __launch_bounds__(256) void final_fc(
    const float* __restrict__ h5, const float* __restrict__ stats5,
    const float* __restrict__ gm5, const float* __restrict__ bt5,
    const float* __restrict__ Wf, const float* __restrict__ bfv,
    float* __restrict__ out) {
  __shared__ float sWf[768 * 6];
  __shared__ float sbf[768];
  __shared__ float sRoot[8][6];
  const int tid = threadIdx.x;
  for (int i = tid; i < 768 * 6; i += 256) sWf[i] = Wf[i];
  for (int i = tid; i < 768; i += 256) sbf[i] = bfv[i];
  const int b0 = blockIdx.x * 8;
  if (tid < 48) {
    int bb = tid / 6, o = tid % 6;
    float mu = stats5[o] * (1.0f / 4096.0f);
    float var = stats5[6 + o] * (1.0f / 4096.0f) - mu * mu;
    float sc = rsqrtf(var + 1e-5f) * gm5[o];
    sRoot[bb][o] = (h5[(size_t)(b0 + bb) * 6 + o] - mu) * sc + bt5[o];
  }
  __syncthreads();
#pragma unroll
  for (int bb = 0; bb < 8; ++bb) {
    float r0 = sRoot[bb][0], r1 = sRoot[bb][1], r2 = sRoot[bb][2];
    float r3 = sRoot[bb][3], r4 = sRoot[bb][4], r5 = sRoot[bb][5];
    for (int d = tid; d < 768; d += 256) {
      const float* wr = &sWf[d * 6];
      float a = sbf[d] + r0 * wr[0] + r1 * wr[1] + r2 * wr[2] +
                r3 * wr[3] + r4 * wr[4] + r5 * wr[5];
      out[(size_t)(b0 + bb) * 768 + d] = a;
    }
  }
}

// ---------------------------------------------------------------------------
// launch
// ---------------------------------------------------------------------------
extern "C" void kernel_launch(void* const* d_in, const int* in_sizes, int n_in,
                              void* d_out, int out_size, void* d_ws,
                              size_t ws_size, hipStream_t stream) {
  const float* x   = (const float*)d_in[0];
  const float* Wg  = (const float*)d_in[1];
  const float* bg  = (const float*)d_in[2];
  const float* W0  = (const float*)d_in[3];
  const float* b0v = (const float*)d_in[4];
  const float* gm0 = (const float*)d_in[5];
  const float* bt0 = (const float*)d_in[6];
  const float* W1  = (const float*)d_in[7];
  const float* b1v = (const float*)d_in[8];
  const float* gm1 = (const float*)d_in[9];
  const float* bt1 = (const float*)d_in[10];
  const float* W2  = (const float*)d_in[11];
  const float* b2v = (const float*)d_in[12];
  const float* gm2 = (const float*)d_in[13];
  const float* bt2 = (const float*)d_in[14];
  const float* W3  = (const float*)d_in[15];
  const float* b3v = (const float*)d_in[16];
  const float* gm3 = (const float*)d_in[17];
  const float* bt3 = (const float*)d_in[18];
  const float* W4  = (const float*)d_in[19];
  const float* b4v = (const float*)d_in[20];
  const float* gm4 = (const float*)d_in[21];
  const float* bt4 = (const float*)d_in[22];
  const float* W5  = (const float*)d_in[23];
  const float* b5v = (const float*)d_in[24];
  const float* gm5 = (const float*)d_in[25];
  const float* bt5 = (const float*)d_in[26];
  const float* Wf  = (const float*)d_in[27];
  const float* bfv = (const float*)d_in[28];

  char* ws = (char*)d_ws;
  unsigned short* Xb  = (unsigned short*)(ws + 0);            // 24,641,536
  unsigned short* Wgb = (unsigned short*)(ws + 24641536ULL);  // 98,566,144
  unsigned short* G   = (unsigned short*)(ws + 123207680ULL); // 134,217,728
  unsigned short* h0  = (unsigned short*)(ws + 257425408ULL); // 100,663,296
  unsigned short* h1  = (unsigned short*)(ws + 358088704ULL); // 25,165,824
  unsigned short* h2  = (unsigned short*)(ws + 383254528ULL); //  6,291,456
  float* h3 = (float*)(ws + 389545984ULL);                    //  3,145,728
  float* h4 = (float*)(ws + 392691712ULL);                    //    786,432
  float* h5 = (float*)(ws + 393478144ULL);                    //     98,304
  float* stats = (float*)(ws + 393576448ULL);                 //    131,072

  hipMemsetAsync(stats, 0, 131072, stream);

  cvt_all<<<dim3(60160), 256, 0, stream>>>(x, Wg, Xb, Wgb);

  gemm_bt<<<dim3(64, 16), 512, 0, stream>>>(Xb, Wgb, bg, G);

  term_layer<unsigned short, unsigned short, 2048, 8, 64, true>
      <<<dim3(32, 64), 256, 0, stream>>>(G, nullptr, nullptr, nullptr, W0, b0v,
                                         h0, stats + 0);
  term_layer<unsigned short, unsigned short, 512, 24, 32, false>
      <<<dim3(16, 64), 256, 0, stream>>>(h0, stats + 0, gm0, bt0, W1, b1v, h1,
                                         stats + 24576);
  term_layer<unsigned short, unsigned short, 128, 24, 32, false>
      <<<dim3(4, 128), 256, 0, stream>>>(h1, stats + 24576, gm1, bt1, W2, b2v,
                                         h2, stats + 30720);
  term_layer<unsigned short, float, 32, 24, 32, false>
      <<<dim3(1, 128), 256, 0, stream>>>(h2, stats + 30720, gm2, bt2, W3, b3v,
                                         h3, stats + 32256);
  term_layer<float, float, 8, 24, 8, false>
      <<<dim3(1, 64), 256, 0, stream>>>(h3, stats + 32256, gm3, bt3, W4, b4v,
                                        h4, stats + 32640);
  term_layer<float, float, 1, 48, 1, false>
      <<<dim3(1, 16), 256, 0, stream>>>(h4, stats + 32640, gm4, bt4, W5, b5v,
                                        h5, stats + 32736);

  final_fc<<<dim3(512), 256, 0, stream>>>(h5, stats + 32736, gm5, bt5, Wf, bfv,
                                          (float*)d_out);
}